// Round 1
// 406.264 us; speedup vs baseline: 1.0739x; 1.0739x over previous
//
#include <hip/hip_runtime.h>
#include <math.h>

// Problem constants (fixed by reference)
#define B_TREES 64
#define N_NODES 65536
#define D 1024          // D_MEM == D_HID == 1024
#define D4 (D/4)        // 256 float4 per row

#define CHUNK 64                    // nodes per block (one boundary max: min seg len >= 341)
#define SUB 8                       // nodes staged in LDS at a time (8 rows * 4KB = 32KB)
#define NSUB (CHUNK/SUB)            // 8 sub-tiles per chunk
#define NCHUNK (N_NODES/CHUNK)      // 1024 blocks
#define NSLOT (2*NCHUNK)            // 2 slots per chunk (<=2 segments per chunk)

// ---------------- Kernel 1: prefix offsets from lens (int32 or int64) -------
__global__ void offsets_kernel(const int* __restrict__ lens32, int* __restrict__ off) {
    if (threadIdx.x == 0 && blockIdx.x == 0) {
        long long s32 = 0;
        for (int b = 0; b < B_TREES; ++b) s32 += lens32[b];
        const bool is32 = (s32 == (long long)N_NODES);
        int acc = 0;
        off[0] = 0;
        for (int b = 0; b < B_TREES; ++b) {
            int len = is32 ? lens32[b] : (int)(((const long long*)lens32)[b]);
            acc += len;
            off[b + 1] = acc;
        }
    }
}

// ---------------- Kernel 2: v = ds @ W   (v[b][m] = sum_h ds[b][h]*W[h][m]) ----
// grid: (4 m-tiles of 256, 16 b-groups of 4, 8 h-chunks of 128); block 256
__global__ void v_kernel(const float* __restrict__ ds, const float* __restrict__ W,
                         float* __restrict__ v) {
    const int m  = blockIdx.x * 256 + threadIdx.x;
    const int b0 = blockIdx.y * 4;
    const int h0 = blockIdx.z * 128;
    float acc[4] = {0.f, 0.f, 0.f, 0.f};
    for (int h = h0; h < h0 + 128; ++h) {
        float wv = W[h * D + m];                // coalesced across threads
        #pragma unroll
        for (int j = 0; j < 4; ++j)
            acc[j] += ds[(b0 + j) * D + h] * wv; // wave-uniform -> scalar loads
    }
    #pragma unroll
    for (int j = 0; j < 4; ++j)
        atomicAdd(&v[(b0 + j) * D + m], acc[j]);
}

// ---------------- Kernel 3: fused scores + per-chunk online softmax + partial ctx
// One block per 64-node chunk. Per 8-node sub-tile:
//   stage mb rows -> LDS (coalesced float4, single HBM read of mb)
//   wave-per-node dot with v[seg] (v row hoisted in regs, reload only at seg cut)
//   block-uniform online softmax: acc[d] += e^{s-m_run} * mb[n][d]  (from same LDS)
// Emits per (chunk, sub-segment) slot: m, z, segid, 1024-dim partial vector.
__global__ __launch_bounds__(256) void fused_kernel(
    const float4* __restrict__ mb, const float4* __restrict__ v,
    const int* __restrict__ off,
    float* __restrict__ m_arr, float* __restrict__ z_arr,
    int* __restrict__ seg_arr, float4* __restrict__ vec)
{
    __shared__ float4 smb[SUB * D4];   // 32 KB staging tile
    __shared__ float  ssc[SUB];        // sub-tile scores
    __shared__ int    sinfo[2];        // {sa, cutg}

    const int tid  = threadIdx.x;
    const int wave = tid >> 6;
    const int lane = tid & 63;
    const int c    = blockIdx.x;
    const int n0   = c * CHUNK;

    if (tid == 0) {
        int lo = 0, hi = B_TREES - 1;          // largest b with off[b] <= n0
        while (lo < hi) { int mid = (lo + hi + 1) >> 1; if (off[mid] <= n0) lo = mid; else hi = mid - 1; }
        sinfo[0] = lo;
        const int nxt = off[lo + 1];
        sinfo[1] = (nxt < n0 + CHUNK) ? nxt : 0x7fffffff;  // cut inside chunk?
    }
    __syncthreads();
    const int sa   = sinfo[0];
    const int cutg = sinfo[1];
    const bool two = (cutg != 0x7fffffff);

    // online-softmax state per sub-segment, replicated identically in all threads
    float  m0 = -INFINITY, z0 = 0.f, m1 = -INFINITY, z1 = 0.f;
    float4 a0 = make_float4(0.f, 0.f, 0.f, 0.f);
    float4 a1 = make_float4(0.f, 0.f, 0.f, 0.f);

    // hoisted v row for this wave's lane slice (reloaded only when segment changes)
    float4 vr0, vr1, vr2, vr3;
    int vcur = -1;

    for (int st = 0; st < NSUB; ++st) {
        const int nb = n0 + st * SUB;
        // ---- stage 8 rows (32 KB) to LDS; 8 independent coalesced float4 loads/thread
        #pragma unroll
        for (int k = 0; k < SUB; ++k)
            smb[k * D4 + tid] = mb[(size_t)(nb + k) * D4 + tid];
        __syncthreads();

        // ---- dots: wave handles nodes k = wave*2 + {0,1}
        #pragma unroll
        for (int q = 0; q < 2; ++q) {
            const int k  = wave * 2 + q;
            const int sg = (nb + k < cutg) ? sa : sa + 1;   // wave-uniform
            if (sg != vcur) {
                vcur = sg;
                vr0 = v[(size_t)sg * D4 +   0 + lane];
                vr1 = v[(size_t)sg * D4 +  64 + lane];
                vr2 = v[(size_t)sg * D4 + 128 + lane];
                vr3 = v[(size_t)sg * D4 + 192 + lane];
            }
            const float4 b0v = smb[k * D4 +   0 + lane];
            const float4 b1v = smb[k * D4 +  64 + lane];
            const float4 b2v = smb[k * D4 + 128 + lane];
            const float4 b3v = smb[k * D4 + 192 + lane];
            float acc = b0v.x*vr0.x + b0v.y*vr0.y + b0v.z*vr0.z + b0v.w*vr0.w;
            acc      += b1v.x*vr1.x + b1v.y*vr1.y + b1v.z*vr1.z + b1v.w*vr1.w;
            acc      += b2v.x*vr2.x + b2v.y*vr2.y + b2v.z*vr2.z + b2v.w*vr2.w;
            acc      += b3v.x*vr3.x + b3v.y*vr3.y + b3v.z*vr3.z + b3v.w*vr3.w;
            #pragma unroll
            for (int o = 32; o > 0; o >>= 1) acc += __shfl_down(acc, o, 64);
            if (lane == 0) ssc[k] = acc;
        }
        __syncthreads();

        // ---- online-softmax weighted accumulate (all branches block-uniform)
        #pragma unroll
        for (int k = 0; k < SUB; ++k) {
            const float  s    = ssc[k];              // LDS broadcast
            const float4 arow = smb[k * D4 + tid];   // contiguous b128, conflict-free
            if (nb + k < cutg) {
                if (s > m0) {
                    const float sc = __expf(m0 - s); // exp(-inf)=0 handles init
                    z0 *= sc; a0.x *= sc; a0.y *= sc; a0.z *= sc; a0.w *= sc;
                    m0 = s;
                }
                const float w = __expf(s - m0);
                z0 += w;
                a0.x += w * arow.x; a0.y += w * arow.y; a0.z += w * arow.z; a0.w += w * arow.w;
            } else {
                if (s > m1) {
                    const float sc = __expf(m1 - s);
                    z1 *= sc; a1.x *= sc; a1.y *= sc; a1.z *= sc; a1.w *= sc;
                    m1 = s;
                }
                const float w = __expf(s - m1);
                z1 += w;
                a1.x += w * arow.x; a1.y += w * arow.y; a1.z += w * arow.z; a1.w += w * arow.w;
            }
        }
        __syncthreads();   // protect smb/ssc before next staging pass
    }

    // ---- emit chunk partials (every slot's segid is written every iteration)
    const int slot0 = 2 * c, slot1 = 2 * c + 1;
    vec[(size_t)slot0 * D4 + tid] = a0;
    if (tid == 0) { m_arr[slot0] = m0; z_arr[slot0] = z0; seg_arr[slot0] = sa; }
    if (two) {
        vec[(size_t)slot1 * D4 + tid] = a1;
        if (tid == 0) { m_arr[slot1] = m1; z_arr[slot1] = z1; seg_arr[slot1] = sa + 1; }
    } else if (tid == 0) {
        seg_arr[slot1] = -1;
    }
}

// ---------------- Kernel 4: combine chunk partials per segment ----------------
// out[b] = (sum_slots e^{m_slot - m_seg} vec_slot) / (sum_slots e^{m_slot - m_seg} z_slot)
__global__ __launch_bounds__(256) void combine_kernel(
    const int* __restrict__ off, const float* __restrict__ m_arr,
    const float* __restrict__ z_arr, const int* __restrict__ seg_arr,
    const float4* __restrict__ vec, float4* __restrict__ out)
{
    const int b = blockIdx.x, t = threadIdx.x;
    const int s0 = off[b], s1 = off[b + 1];
    const int c0 = s0 / CHUNK, c1 = (s1 - 1) / CHUNK;   // chunks intersecting segment b

    float mseg = -INFINITY;
    for (int cc = c0; cc <= c1; ++cc) {
        #pragma unroll
        for (int j = 0; j < 2; ++j) {
            const int sl = 2 * cc + j;
            if (seg_arr[sl] == b) mseg = fmaxf(mseg, m_arr[sl]);
        }
    }
    float zseg = 0.f;
    float4 acc = make_float4(0.f, 0.f, 0.f, 0.f);
    for (int cc = c0; cc <= c1; ++cc) {
        #pragma unroll
        for (int j = 0; j < 2; ++j) {
            const int sl = 2 * cc + j;
            if (seg_arr[sl] == b) {                     // block-uniform
                const float sc = __expf(m_arr[sl] - mseg);
                zseg += sc * z_arr[sl];
                const float4 vv = vec[(size_t)sl * D4 + t];
                acc.x += sc * vv.x; acc.y += sc * vv.y;
                acc.z += sc * vv.z; acc.w += sc * vv.w;
            }
        }
    }
    const float inv = 1.f / zseg;
    acc.x *= inv; acc.y *= inv; acc.z *= inv; acc.w *= inv;
    out[(size_t)b * D4 + t] = acc;
}

extern "C" void kernel_launch(void* const* d_in, const int* in_sizes, int n_in,
                              void* d_out, int out_size, void* d_ws, size_t ws_size,
                              hipStream_t stream) {
    const float* mb   = (const float*)d_in[0];       // [N, 1024]
    const float* ds   = (const float*)d_in[1];       // [64, 1024]
    const float* W    = (const float*)d_in[2];       // [1024, 1024]
    const int*   lens = (const int*)d_in[3];         // [64] int32 (or int64 — autodetected)
    float*       out  = (float*)d_out;               // [64, 1024]

    // workspace layout (~8.6 MB): off | v | m | z | seg | vec
    char*  ws      = (char*)d_ws;
    int*   off     = (int*)ws;                                   // 65 ints (512 B region)
    float* v       = (float*)(ws + 512);                         // 64*1024 floats (256 KB)
    float* m_arr   = (float*)(ws + 512 + 64 * D * 4);            // NSLOT floats
    float* z_arr   = m_arr + NSLOT;
    int*   seg_arr = (int*)(z_arr + NSLOT);
    float* vec     = (float*)((char*)(seg_arr + NSLOT));         // NSLOT * 1024 floats (8 MB), 16B-aligned

    // zero the only atomic-accumulation target (all other ws reads are written this launch)
    hipMemsetAsync(v, 0, 64 * D * sizeof(float), stream);

    offsets_kernel<<<1, 64, 0, stream>>>(lens, off);

    {
        dim3 grid(4, 16, 8);
        v_kernel<<<grid, 256, 0, stream>>>(ds, W, v);
    }

    fused_kernel<<<NCHUNK, 256, 0, stream>>>(
        (const float4*)mb, (const float4*)v, off, m_arr, z_arr, seg_arr, (float4*)vec);

    combine_kernel<<<B_TREES, 256, 0, stream>>>(
        off, m_arr, z_arr, seg_arr, (const float4*)vec, (float4*)out);
}